// Round 6
// baseline (404.457 us; speedup 1.0000x reference)
//
#include <hip/hip_runtime.h>
#include <hip/hip_cooperative_groups.h>
#include <cstdint>
#include <cstddef>

namespace cg = cooperative_groups;

#define B_  32
#define CIN 128
#define P_  256
#define E_  512
#define H_  64
#define W_  64
#define HO  32
#define WO  32

// padded abits geometry: 65x65 uint4 pixels per image, pad row 0 / col 0 are zero
#define APITCH 65
#define APIX   4225   // 65*65

// ---------------- K1: merged bias GEMMs + weight prep ----------------
__global__ void k_bw(const float* __restrict__ emb,
                     const float* __restrict__ m1_w, const float* __restrict__ m1_b,
                     const float* __restrict__ m2_w, const float* __restrict__ m2_b,
                     const float* __restrict__ m3_w, const float* __restrict__ m3_b,
                     const float* __restrict__ conv_w,
                     float* __restrict__ b1, float* __restrict__ b2, float* __restrict__ b3,
                     float* __restrict__ sf, unsigned int* __restrict__ wbits,
                     int* __restrict__ cwrow, int* __restrict__ cwcol, int* __restrict__ cw0,
                     float* __restrict__ s1, float* __restrict__ s2) {
    int bid = blockIdx.x;
    int tid = threadIdx.x;
    int wave = tid >> 6, lane = tid & 63;

    if (bid < B_ * 160) {
        // ---- bias path: wave-per-row, silu inline ----
        int n = bid / 160, rg = bid % 160;
        int row = rg * 4 + wave;         // 0..639
        const float* sp = emb + n * E_;
        const float* wrow; float bias; float* dst;
        if (row < CIN)            { wrow = m1_w + (size_t)row * E_;          bias = m1_b[row]; dst = b1 + n * CIN + row; }
        else if (row < CIN + P_)  { int c = row - CIN;      wrow = m2_w + (size_t)c * E_; bias = m2_b[c]; dst = b2 + n * P_ + c; }
        else                      { int c = row - CIN - P_; wrow = m3_w + (size_t)c * E_; bias = m3_b[c]; dst = b3 + n * P_ + c; }
        float acc = 0.f;
        #pragma unroll
        for (int j = 0; j < 8; j++) {
            int k = j * 64 + lane;
            float e = sp[k];
            acc += (e / (1.f + expf(-e))) * wrow[k];
        }
        #pragma unroll
        for (int off = 32; off > 0; off >>= 1) acc += __shfl_down(acc, off);
        if (lane == 0) *dst = acc + bias;
        return;
    }

    // ---- weight-prep path: 2 out-channels per block ----
    int base = (bid - B_ * 160) * 2;
    int oc = base + (wave >> 1);
    int iw = wave & 1;                   // which 64-channel half
    int i  = iw * 64 + lane;             // input channel 0..127
    if (lane == 0 && iw == 0) { s1[oc] = 0.f; s2[oc] = 0.f; }
    const float* wp = conv_w + ((size_t)oc * CIN + i) * 9;
    float w[9]; float s = 0.f;
    int pc[9];
    #pragma unroll
    for (int t = 0; t < 9; t++) { w[t] = wp[t]; s += fabsf(w[t]); }
    #pragma unroll
    for (int t = 0; t < 9; t++) {
        unsigned long long m = __ballot(w[t] < 0.f);
        pc[t] = __popcll(m);             // neg-count for this 64-ch half (wave-uniform)
        if (lane == 0) {
            wbits[oc * 36 + t * 4 + iw * 2 + 0] = (unsigned int)(m & 0xffffffffull);
            wbits[oc * 36 + t * 4 + iw * 2 + 1] = (unsigned int)(m >> 32);
        }
    }
    #pragma unroll
    for (int off = 32; off > 0; off >>= 1) s += __shfl_down(s, off);
    __shared__ float sred[4];
    __shared__ int spc[4][9];
    if (lane == 0) {
        sred[wave] = s;
        #pragma unroll
        for (int t = 0; t < 9; t++) spc[wave][t] = pc[t];
    }
    __syncthreads();
    if (tid == 0) {
        sf[base] = (sred[0] + sred[1]) / 1152.f;
        int c_[9];
        #pragma unroll
        for (int t = 0; t < 9; t++) c_[t] = spc[0][t] + spc[1][t];   // neg count over 128 ch
        cwrow[base] = 384 - 2 * (c_[0] + c_[1] + c_[2]);   // taps {0,1,2}  (r==-1 row)
        cwcol[base] = 384 - 2 * (c_[0] + c_[3] + c_[6]);   // taps {0,3,6}  (c==-1 col)
        cw0[base]   = 128 - 2 * c_[0];                     // corner tap
    } else if (tid == 128) {
        sf[base + 1] = (sred[2] + sred[3]) / 1152.f;
        int c_[9];
        #pragma unroll
        for (int t = 0; t < 9; t++) c_[t] = spc[2][t] + spc[3][t];
        cwrow[base + 1] = 384 - 2 * (c_[0] + c_[1] + c_[2]);
        cwcol[base + 1] = 384 - 2 * (c_[0] + c_[3] + c_[6]);
        cw0[base + 1]   = 128 - 2 * c_[0];
    }
}

// ---------------- K2: cooperative fused prep -> conv -> stats -> epilogue ----------------
// grid = 1024 blocks x 256 threads, co-resident (4 blocks/CU x 256 CU).
// phase 0: bid = n*32 + h2     : bitpack sign(x+b1) into padded abits + 2x2 avgpool
// phase A: bid = n*32 + ocg*4 + strip : XNOR conv, 32 oc x 256 pix -> y in LDS + BN stats
// phase B: BN finalize + skip + bias2 + PReLU + bias3 -> out, straight from LDS y
__global__ void __launch_bounds__(256, 4)
k_fused(const float* __restrict__ x, const float* __restrict__ b1,
        const unsigned int* __restrict__ wbits,
        const int* __restrict__ cwrow, const int* __restrict__ cwcol, const int* __restrict__ cw0,
        const float* __restrict__ sf, float* __restrict__ s1, float* __restrict__ s2,
        const float* __restrict__ bn_g, const float* __restrict__ bn_b,
        const float* __restrict__ b2, const float* __restrict__ b3,
        const float* __restrict__ prelu_a,
        unsigned int* __restrict__ abits, float* __restrict__ xpool, float* __restrict__ out) {
    cg::grid_group grid = cg::this_grid();
    __shared__ float sb1[CIN];
    __shared__ short y_lds[32][256];             // conv result, survives the stats barrier
    __shared__ int red1[32][33], red2[32][33];   // padded: conflict-free

    int bid = blockIdx.x;
    int tid = threadIdx.x;
    int n = bid >> 5;
    int wave = tid >> 6, lane = tid & 63;

    // ================= phase 0: bitpack + pool =================
    {
        int h2 = bid & 31;
        for (int i = tid; i < CIN; i += 256) sb1[i] = b1[n * CIN + i];
        __syncthreads();

        // zero the pad (row 0 and col 0 of the 65x65 layout), once per image
        if (h2 == 0) {
            for (int i = tid; i < 129; i += 256) {
                size_t idx = (i < 65) ? ((size_t)n * APIX + i)
                                      : ((size_t)n * APIX + (size_t)(i - 64) * APITCH);
                ((uint4*)abits)[idx] = make_uint4(0u, 0u, 0u, 0u);
            }
        }

        int wg = wave;                       // 32-channel word group
        int w = lane, w2 = w >> 1;
        const float* xb = x + ((size_t)(n * CIN + wg * 32)) * (H_ * W_) + (size_t)(2 * h2) * W_ + w;
        float* xpq = xpool + ((size_t)(n * CIN + wg * 32)) * (HO * WO) + h2 * WO + w2;
        unsigned int mt = 0, mb = 0;
        #pragma unroll 8
        for (int j = 0; j < 32; j++) {
            float vt = xb[(size_t)j * (H_ * W_)];
            float vb = xb[(size_t)j * (H_ * W_) + W_];
            float bc = sb1[wg * 32 + j];
            mt |= (vt + bc < 0.f ? 1u : 0u) << j;
            mb |= (vb + bc < 0.f ? 1u : 0u) << j;
            float p = vt + vb;
            p += __shfl_xor(p, 1);
            if ((w & 1) == 0) xpq[(size_t)j * (HO * WO)] = 0.25f * p;
        }
        size_t basei = ((size_t)n * APIX + (size_t)(2 * h2 + 1) * APITCH + (w + 1)) * 4 + wg;
        abits[basei] = mt;
        abits[basei + APITCH * 4] = mb;
    }
    grid.sync();

    // ================= phase A: XNOR conv + BN stats =================
    int strip = bid & 3, ocg = (bid >> 2) & 7;
    int ocb = ocg * 32;
    int oh = strip * 8 + (tid >> 5), ow = tid & 31;
    bool r0 = (oh == 0), c0 = (ow == 0);
    bool rc0 = r0 && c0;

    // 9 image taps -> VGPRs, pinned so the compiler cannot rematerialize them
    const uint4* asrc = ((const uint4*)abits) + (size_t)n * APIX;
    uint4 img[9];
    #pragma unroll
    for (int kh = 0; kh < 3; kh++) {
        #pragma unroll
        for (int kw = 0; kw < 3; kw++) {
            img[kh * 3 + kw] = asrc[(2 * oh + kh) * APITCH + (2 * ow + kw)];
        }
    }
    #pragma unroll
    for (int t = 0; t < 9; t++) {
        asm volatile("" : "+v"(img[t].x), "+v"(img[t].y), "+v"(img[t].z), "+v"(img[t].w));
    }

    const uint4* wp = ((const uint4*)wbits) + (size_t)ocb * 9;
    #pragma unroll 4
    for (int o = 0; o < 32; o++) {
        int popsum = 0;
        #pragma unroll
        for (int t = 0; t < 9; t++) {
            uint4 a = img[t];
            uint4 w = wp[o * 9 + t];
            popsum += __popc(a.x ^ w.x) + __popc(a.y ^ w.y) +
                      __popc(a.z ^ w.z) + __popc(a.w ^ w.w);
        }
        // border correction: padded taps saw a=+1 (bits 0); subtract their weight sums
        int corr = (r0 ? cwrow[ocb + o] : 0) + (c0 ? cwcol[ocb + o] : 0) - (rc0 ? cw0[ocb + o] : 0);
        int s = 1152 - 2 * popsum - corr;            // [-1152, 1152]
        y_lds[o][tid] = (short)s;
        int vs = s, v2 = s * s;
        vs += __shfl_down(vs, 32); v2 += __shfl_down(v2, 32);
        vs += __shfl_down(vs, 16); v2 += __shfl_down(v2, 16);
        vs += __shfl_down(vs, 8);  v2 += __shfl_down(v2, 8);
        if (lane < 8) { red1[o][wave * 8 + lane] = vs; red2[o][wave * 8 + lane] = v2; }
    }
    __syncthreads();
    if (tid < 64) {
        int o = tid & 31;
        int a = 0;
        if (tid < 32) {
            #pragma unroll
            for (int p = 0; p < 32; p++) a += red1[o][p];
            atomicAdd(s1 + ocb + o, (float)a);
        } else {
            #pragma unroll
            for (int p = 0; p < 32; p++) a += red2[o][p];
            atomicAdd(s2 + ocb + o, (float)a);   // <= 3.4e8, fits int32 exactly pre-cast
        }
    }
    grid.sync();

    // ================= phase B: BN finalize + epilogue -> out =================
    {
        const float inv = 1.f / (B_ * HO * WO);
        int pixoff = strip * 256 + tid;          // = oh*32 + ow
        #pragma unroll 4
        for (int o = 0; o < 32; o++) {
            int c = ocb + o;
            float sc = sf[c];
            float m = sc * s1[c] * inv;                          // mean of sf*s
            float var = fmaf(-m, m, sc * sc * s2[c] * inv);      // E[(sf*s)^2] - mean^2
            float r = rsqrtf(var + 1e-5f) * bn_g[c];
            float add0 = bn_b[c] + b2[n * P_ + c];
            float aP = prelu_a[c];
            float b3v = b3[n * P_ + c];
            float yv = (float)y_lds[o][tid];
            float xv = xpool[(((size_t)n * CIN + (c & 127)) << 10) + pixoff];
            float o0 = (sc * yv - m) * r + add0 + xv;
            o0 = (o0 > 0.f ? o0 : aP * o0) + b3v;
            out[(((size_t)n * P_ + c) << 10) + pixoff] = o0;
        }
    }
}

extern "C" void kernel_launch(void* const* d_in, const int* in_sizes, int n_in,
                              void* d_out, int out_size, void* d_ws, size_t ws_size,
                              hipStream_t stream) {
    const float* x      = (const float*)d_in[0];
    const float* emb    = (const float*)d_in[1];
    const float* m1_w   = (const float*)d_in[2];
    const float* m1_b   = (const float*)d_in[3];
    const float* conv_w = (const float*)d_in[4];
    // d_in[5] = conv_b : cancels exactly under training-mode BN, unused
    const float* bn_g   = (const float*)d_in[6];
    const float* bn_b   = (const float*)d_in[7];
    const float* m2_w   = (const float*)d_in[8];
    const float* m2_b   = (const float*)d_in[9];
    const float* prelu_a= (const float*)d_in[10];
    const float* m3_w   = (const float*)d_in[11];
    const float* m3_b   = (const float*)d_in[12];

    float* out = (float*)d_out;   // written once, by k_fused phase B

    // workspace carve-up (f32 words)
    float* wsf = (float*)d_ws;
    float* b1    = wsf;                  // 32*128
    float* b2    = wsf + 4096;           // 32*256
    float* b3    = wsf + 12288;          // 32*256
    float* sf    = wsf + 20480;          // 256
    float* s1    = wsf + 20736;          // 256  (zeroed by k_bw)
    float* s2    = wsf + 20992;          // 256  (zeroed by k_bw)
    unsigned int* wbits = (unsigned int*)(wsf + 21248);   // 256*36 u32
    int* cwrow = (int*)(wsf + 30464);    // 256
    int* cwcol = (int*)(wsf + 30720);    // 256
    int* cw0   = (int*)(wsf + 30976);    // 256
    unsigned int* abits = (unsigned int*)(wsf + 31232);   // 32*65*65*4 u32 (~2.2 MiB)
    float* xpool = wsf + 572032;         // 32*128*32*32 f32 (16 MiB)

    k_bw <<<B_ * 160 + P_ / 2, 256, 0, stream>>>(emb, m1_w, m1_b, m2_w, m2_b, m3_w, m3_b,
                                                 conv_w, b1, b2, b3, sf, wbits,
                                                 cwrow, cwcol, cw0, s1, s2);

    void* kargs[17];
    kargs[0]  = (void*)&x;
    kargs[1]  = (void*)&b1;
    kargs[2]  = (void*)&wbits;
    kargs[3]  = (void*)&cwrow;
    kargs[4]  = (void*)&cwcol;
    kargs[5]  = (void*)&cw0;
    kargs[6]  = (void*)&sf;
    kargs[7]  = (void*)&s1;
    kargs[8]  = (void*)&s2;
    kargs[9]  = (void*)&bn_g;
    kargs[10] = (void*)&bn_b;
    kargs[11] = (void*)&b2;
    kargs[12] = (void*)&b3;
    kargs[13] = (void*)&prelu_a;
    kargs[14] = (void*)&abits;
    kargs[15] = (void*)&xpool;
    kargs[16] = (void*)&out;
    hipLaunchCooperativeKernel((void*)k_fused, dim3(B_ * 32), dim3(256), kargs, 0, stream);
}

// Round 7
// 186.164 us; speedup vs baseline: 2.1726x; 2.1726x over previous
//
#include <hip/hip_runtime.h>
#include <cstdint>
#include <cstddef>

#define B_  32
#define CIN 128
#define P_  256
#define E_  512
#define H_  64
#define W_  64
#define HO  32
#define WO  32

// padded abits geometry: 65x65 uint4 pixels per image, pad row 0 / col 0 are zero
#define APITCH 65
#define APIX   4225   // 65*65

// ---------------- K1: merged bias GEMMs + weight prep ----------------
__global__ void k_bw(const float* __restrict__ emb,
                     const float* __restrict__ m1_w, const float* __restrict__ m1_b,
                     const float* __restrict__ m2_w, const float* __restrict__ m2_b,
                     const float* __restrict__ m3_w, const float* __restrict__ m3_b,
                     const float* __restrict__ conv_w,
                     float* __restrict__ b1, float* __restrict__ b2, float* __restrict__ b3,
                     float* __restrict__ sf, unsigned int* __restrict__ wbits,
                     int* __restrict__ cwrow, int* __restrict__ cwcol, int* __restrict__ cw0,
                     float* __restrict__ s1, float* __restrict__ s2) {
    int bid = blockIdx.x;
    int tid = threadIdx.x;
    int wave = tid >> 6, lane = tid & 63;

    if (bid < B_ * 160) {
        // ---- bias path: wave-per-row, silu inline ----
        int n = bid / 160, rg = bid % 160;
        int row = rg * 4 + wave;         // 0..639
        const float* sp = emb + n * E_;
        const float* wrow; float bias; float* dst;
        if (row < CIN)            { wrow = m1_w + (size_t)row * E_;          bias = m1_b[row]; dst = b1 + n * CIN + row; }
        else if (row < CIN + P_)  { int c = row - CIN;      wrow = m2_w + (size_t)c * E_; bias = m2_b[c]; dst = b2 + n * P_ + c; }
        else                      { int c = row - CIN - P_; wrow = m3_w + (size_t)c * E_; bias = m3_b[c]; dst = b3 + n * P_ + c; }
        float acc = 0.f;
        #pragma unroll
        for (int j = 0; j < 8; j++) {
            int k = j * 64 + lane;
            float e = sp[k];
            acc += (e / (1.f + expf(-e))) * wrow[k];
        }
        #pragma unroll
        for (int off = 32; off > 0; off >>= 1) acc += __shfl_down(acc, off);
        if (lane == 0) *dst = acc + bias;
        return;
    }

    // ---- weight-prep path: 2 out-channels per block ----
    int base = (bid - B_ * 160) * 2;
    int oc = base + (wave >> 1);
    int iw = wave & 1;                   // which 64-channel half
    int i  = iw * 64 + lane;             // input channel 0..127
    if (lane == 0 && iw == 0) { s1[oc] = 0.f; s2[oc] = 0.f; }
    const float* wp = conv_w + ((size_t)oc * CIN + i) * 9;
    float w[9]; float s = 0.f;
    int pc[9];
    #pragma unroll
    for (int t = 0; t < 9; t++) { w[t] = wp[t]; s += fabsf(w[t]); }
    #pragma unroll
    for (int t = 0; t < 9; t++) {
        unsigned long long m = __ballot(w[t] < 0.f);
        pc[t] = __popcll(m);             // neg-count for this 64-ch half (wave-uniform)
        if (lane == 0) {
            wbits[oc * 36 + t * 4 + iw * 2 + 0] = (unsigned int)(m & 0xffffffffull);
            wbits[oc * 36 + t * 4 + iw * 2 + 1] = (unsigned int)(m >> 32);
        }
    }
    #pragma unroll
    for (int off = 32; off > 0; off >>= 1) s += __shfl_down(s, off);
    __shared__ float sred[4];
    __shared__ int spc[4][9];
    if (lane == 0) {
        sred[wave] = s;
        #pragma unroll
        for (int t = 0; t < 9; t++) spc[wave][t] = pc[t];
    }
    __syncthreads();
    if (tid == 0) {
        sf[base] = (sred[0] + sred[1]) / 1152.f;
        int c_[9];
        #pragma unroll
        for (int t = 0; t < 9; t++) c_[t] = spc[0][t] + spc[1][t];   // neg count over 128 ch
        cwrow[base] = 384 - 2 * (c_[0] + c_[1] + c_[2]);   // taps {0,1,2}  (r==-1 row)
        cwcol[base] = 384 - 2 * (c_[0] + c_[3] + c_[6]);   // taps {0,3,6}  (c==-1 col)
        cw0[base]   = 128 - 2 * c_[0];                     // corner tap
    } else if (tid == 128) {
        sf[base + 1] = (sred[2] + sred[3]) / 1152.f;
        int c_[9];
        #pragma unroll
        for (int t = 0; t < 9; t++) c_[t] = spc[2][t] + spc[3][t];
        cwrow[base + 1] = 384 - 2 * (c_[0] + c_[1] + c_[2]);
        cwcol[base + 1] = 384 - 2 * (c_[0] + c_[3] + c_[6]);
        cw0[base + 1]   = 128 - 2 * c_[0];
    }
}

// ---------------- K2: fused sign(x+b1) bit-pack (padded) + 2x2 avgpool, float2 loads ----------------
// lane = (row, w-pair): row = lane>>5 (0/1), w = 2*(lane&31); wave = 32-channel word group.
// Each thread loads float2 over w (8B), builds TWO abits words locally, pools via shfl_xor(32).
__global__ void k_prep(const float* __restrict__ x, const float* __restrict__ b1,
                       unsigned int* __restrict__ abits, float* __restrict__ xpool) {
    __shared__ float sb1[CIN];
    int n = blockIdx.x >> 5, h2 = blockIdx.x & 31;
    int tid = threadIdx.x;
    for (int i = tid; i < CIN; i += 256) sb1[i] = b1[n * CIN + i];
    __syncthreads();

    // zero the pad (row 0 and col 0 of the 65x65 layout), once per image
    if (h2 == 0) {
        for (int i = tid; i < 129; i += 256) {
            size_t idx = (i < 65) ? ((size_t)n * APIX + i)                    // r=0, c=0..64
                                  : ((size_t)n * APIX + (size_t)(i - 64) * APITCH); // c=0, r=1..64
            ((uint4*)abits)[idx] = make_uint4(0u, 0u, 0u, 0u);
        }
    }

    int wg = tid >> 6, lane = tid & 63;
    int row = lane >> 5;                 // 0 or 1
    int wp2 = lane & 31;                 // w-pair index; w = 2*wp2
    int h = 2 * h2 + row;
    const float* xb = x + ((size_t)(n * CIN + wg * 32)) * (H_ * W_) + (size_t)h * W_ + 2 * wp2;
    float* xpq = xpool + ((size_t)(n * CIN + wg * 32)) * (HO * WO) + h2 * WO + wp2;
    unsigned int m0 = 0, m1 = 0;
    #pragma unroll 8
    for (int j = 0; j < 32; j++) {
        float2 v = *(const float2*)(xb + (size_t)j * (H_ * W_));
        float bc = sb1[wg * 32 + j];
        m0 |= (v.x + bc < 0.f ? 1u : 0u) << j;
        m1 |= (v.y + bc < 0.f ? 1u : 0u) << j;
        float p = v.x + v.y;
        p += __shfl_xor(p, 32);          // partner row, same w-pair, same wg
        if (row == 0) xpq[(size_t)j * (HO * WO)] = 0.25f * p;
    }
    // two abits words: pixels (h, 2*wp2) and (h, 2*wp2+1) -> padded cols +1
    size_t basei = ((size_t)n * APIX + (size_t)(h + 1) * APITCH + (2 * wp2 + 1)) * 4 + wg;
    abits[basei]     = m0;
    abits[basei + 4] = m1;
}

// ---------------- K3: XNOR conv (padded, img pinned) -> int16 y + fused BN int stats ----------------
// bid = n*64 + og*4 + strip; each block: 16 out-channels x one 8-row strip. grid 2048.
__global__ void __launch_bounds__(256, 6) k_convstat(const unsigned int* __restrict__ abits,
                                                     const unsigned int* __restrict__ wbits,
                                                     const int* __restrict__ cwrow,
                                                     const int* __restrict__ cwcol,
                                                     const int* __restrict__ cw0,
                                                     short* __restrict__ y16,
                                                     float* __restrict__ s1, float* __restrict__ s2) {
    __shared__ int red1[16][33], red2[16][33];   // padded: conflict-free
    int bid = blockIdx.x;
    int strip = bid & 3, og = (bid >> 2) & 15, n = bid >> 6;
    int tid = threadIdx.x;
    int wave = tid >> 6, lane = tid & 63;
    int oh = strip * 8 + (tid >> 5), ow = tid & 31;
    bool r0 = (oh == 0), c0 = (ow == 0);
    bool rc0 = r0 && c0;

    // 9 image taps -> VGPRs, PINNED so the compiler cannot rematerialize them
    const uint4* asrc = ((const uint4*)abits) + (size_t)n * APIX;
    uint4 img[9];
    #pragma unroll
    for (int kh = 0; kh < 3; kh++) {
        #pragma unroll
        for (int kw = 0; kw < 3; kw++) {
            img[kh * 3 + kw] = asrc[(2 * oh + kh) * APITCH + (2 * ow + kw)];
        }
    }
    #pragma unroll
    for (int t = 0; t < 9; t++) {
        asm volatile("" : "+v"(img[t].x), "+v"(img[t].y), "+v"(img[t].z), "+v"(img[t].w));
    }

    int ocb = og * 16;
    const uint4* wp = ((const uint4*)wbits) + (size_t)ocb * 9;
    short* yp = y16 + (((size_t)n * P_ + ocb) << 10) + strip * 256 + tid;
    #pragma unroll 4
    for (int o = 0; o < 16; o++) {
        int popsum = 0;
        #pragma unroll
        for (int t = 0; t < 9; t++) {
            uint4 a = img[t];
            uint4 w = wp[o * 9 + t];
            popsum += __popc(a.x ^ w.x) + __popc(a.y ^ w.y) +
                      __popc(a.z ^ w.z) + __popc(a.w ^ w.w);
        }
        // border correction: padded taps saw a=+1 (bits 0); subtract their weight sums
        int corr = (r0 ? cwrow[ocb + o] : 0) + (c0 ? cwcol[ocb + o] : 0) - (rc0 ? cw0[ocb + o] : 0);
        int s = 1152 - 2 * popsum - corr;            // [-1152, 1152]
        yp[(size_t)o << 10] = (short)s;
        int vs = s, v2 = s * s;
        vs += __shfl_down(vs, 32); v2 += __shfl_down(v2, 32);
        vs += __shfl_down(vs, 16); v2 += __shfl_down(v2, 16);
        vs += __shfl_down(vs, 8);  v2 += __shfl_down(v2, 8);
        if (lane < 8) { red1[o][wave * 8 + lane] = vs; red2[o][wave * 8 + lane] = v2; }
    }
    __syncthreads();
    if (tid < 32) {
        int o = tid & 15;
        int a = 0;
        if (tid < 16) {
            #pragma unroll
            for (int p = 0; p < 32; p++) a += red1[o][p];
            atomicAdd(s1 + ocb + o, (float)a);
        } else {
            #pragma unroll
            for (int p = 0; p < 32; p++) a += red2[o][p];
            atomicAdd(s2 + ocb + o, (float)a);   // <= 1.36e9, fits int32 exactly pre-cast
        }
    }
}

// ---------------- K4: BN finalize+apply + skip + bias2 + PReLU + bias3 -> d_out ----------------
__global__ void k_epi(const short* __restrict__ y16, const float* __restrict__ xpool,
                      const float* __restrict__ sf,
                      const float* __restrict__ s1, const float* __restrict__ s2,
                      const float* __restrict__ bn_g, const float* __restrict__ bn_b,
                      const float* __restrict__ b2, const float* __restrict__ b3,
                      const float* __restrict__ prelu_a, float* __restrict__ out) {
    int i4 = blockIdx.x * blockDim.x + threadIdx.x;   // 4-pixel index
    int pix4 = i4 & 255;
    int c = (i4 >> 8) & 255;
    int n = i4 >> 16;
    short4 yv = ((const short4*)y16)[i4];
    float4 xv = ((const float4*)xpool)[((n * CIN + (c & 127)) << 8) + pix4];
    const float inv = 1.f / (B_ * HO * WO);
    float sc = sf[c];
    float m = sc * s1[c] * inv;                          // mean of sf*s
    float var = fmaf(-m, m, sc * sc * s2[c] * inv);      // E[(sf*s)^2] - mean^2
    float r = rsqrtf(var + 1e-5f) * bn_g[c];
    float add0 = bn_b[c] + b2[n * P_ + c];
    float a = prelu_a[c];
    float b3v = b3[n * P_ + c];
    float o0 = (sc * (float)yv.x - m) * r + add0 + xv.x; o0 = (o0 > 0.f ? o0 : a * o0) + b3v;
    float o1 = (sc * (float)yv.y - m) * r + add0 + xv.y; o1 = (o1 > 0.f ? o1 : a * o1) + b3v;
    float o2 = (sc * (float)yv.z - m) * r + add0 + xv.z; o2 = (o2 > 0.f ? o2 : a * o2) + b3v;
    float o3 = (sc * (float)yv.w - m) * r + add0 + xv.w; o3 = (o3 > 0.f ? o3 : a * o3) + b3v;
    ((float4*)out)[i4] = make_float4(o0, o1, o2, o3);
}

extern "C" void kernel_launch(void* const* d_in, const int* in_sizes, int n_in,
                              void* d_out, int out_size, void* d_ws, size_t ws_size,
                              hipStream_t stream) {
    const float* x      = (const float*)d_in[0];
    const float* emb    = (const float*)d_in[1];
    const float* m1_w   = (const float*)d_in[2];
    const float* m1_b   = (const float*)d_in[3];
    const float* conv_w = (const float*)d_in[4];
    // d_in[5] = conv_b : cancels exactly under training-mode BN, unused
    const float* bn_g   = (const float*)d_in[6];
    const float* bn_b   = (const float*)d_in[7];
    const float* m2_w   = (const float*)d_in[8];
    const float* m2_b   = (const float*)d_in[9];
    const float* prelu_a= (const float*)d_in[10];
    const float* m3_w   = (const float*)d_in[11];
    const float* m3_b   = (const float*)d_in[12];

    float* out = (float*)d_out;   // written once, by k_epi

    // workspace carve-up (f32 words)
    float* wsf = (float*)d_ws;
    float* b1    = wsf;                  // 32*128
    float* b2    = wsf + 4096;           // 32*256
    float* b3    = wsf + 12288;          // 32*256
    float* sf    = wsf + 20480;          // 256
    float* s1    = wsf + 20736;          // 256  (zeroed by k_bw)
    float* s2    = wsf + 20992;          // 256  (zeroed by k_bw)
    unsigned int* wbits = (unsigned int*)(wsf + 21248);   // 256*36 u32
    int* cwrow = (int*)(wsf + 30464);    // 256
    int* cwcol = (int*)(wsf + 30720);    // 256
    int* cw0   = (int*)(wsf + 30976);    // 256
    unsigned int* abits = (unsigned int*)(wsf + 31232);   // 32*65*65*4 u32 (~2.2 MiB)
    float* xpool = wsf + 572032;         // 32*128*32*32 f32 (16 MiB)
    short* y16   = (short*)(wsf + 4766336);               // 32*256*1024 i16 (16 MiB)

    k_bw      <<<B_ * 160 + P_ / 2, 256, 0, stream>>>(emb, m1_w, m1_b, m2_w, m2_b, m3_w, m3_b,
                                                      conv_w, b1, b2, b3, sf, wbits,
                                                      cwrow, cwcol, cw0, s1, s2);
    k_prep    <<<B_ * 32, 256, 0, stream>>>(x, b1, abits, xpool);
    k_convstat<<<B_ * 64, 256, 0, stream>>>(abits, wbits, cwrow, cwcol, cw0, y16, s1, s2);
    k_epi     <<<(B_ * P_ * HO * WO) / (4 * 256), 256, 0, stream>>>(y16, xpool, sf, s1, s2,
                                                                    bn_g, bn_b, b2, b3, prelu_a, out);
}